// Round 5
// baseline (206.245 us; speedup 1.0000x reference)
//
#include <hip/hip_runtime.h>
#include <hip/hip_bf16.h>
#include <math.h>

#define BATCH 64
#define TT 512
#define HH 1024
#define KK 8
#define ROWS (BATCH * TT)          // 32768
#define SEG  (ROWS * KK)           // 262144 floats per logits output
#define TAGS_OFF (3 * SEG)         // 786432
#define LOSS_OFF (TAGS_OFF + BATCH * 3 * TT)  // 884736

#define FMA8(base, w0, w1, xe)                          \
    acc[base + 0] = fmaf(xe, w0.x, acc[base + 0]);      \
    acc[base + 1] = fmaf(xe, w0.y, acc[base + 1]);      \
    acc[base + 2] = fmaf(xe, w0.z, acc[base + 2]);      \
    acc[base + 3] = fmaf(xe, w0.w, acc[base + 3]);      \
    acc[base + 4] = fmaf(xe, w1.x, acc[base + 4]);      \
    acc[base + 5] = fmaf(xe, w1.y, acc[base + 5]);      \
    acc[base + 6] = fmaf(xe, w1.z, acc[base + 6]);      \
    acc[base + 7] = fmaf(xe, w1.w, acc[base + 7]);

// ---------------------------------------------------------------------------
// Kernel 1: fused 3-head GEMM. 512 blocks x 4 waves, per-wave private
// double-buffered pipeline. Weight pointers laundered into VGPRs so weight
// reads are VECTOR loads (vmcnt, deep in flight) instead of s_loads whose
// lgkmcnt(0) drains serialized every h-group (R4: VGPR=68 proved scalar-ization).
// red[] overlays the x-tile LDS (union) -> 35 KB -> 3-4 blocks/CU.
// ---------------------------------------------------------------------------
#define XL(wv, buf, hh, col) smem[(((wv) * 2 + (buf)) * 16 + (hh)) * 68 + (col)]

__global__ __launch_bounds__(256, 3) void gemm_heads(
    const float* __restrict__ enc,
    const float* __restrict__ Wt, const float* __restrict__ bt,
    const float* __restrict__ Wp, const float* __restrict__ bpv,
    const float* __restrict__ Wm, const float* __restrict__ bm,
    float* __restrict__ out)
{
    __shared__ float smem[4 * 2 * 16 * 68];   // 34.8 KB; red overlays after sync

    int tid  = threadIdx.x;
    int lane = tid & 63;
    int wv   = __builtin_amdgcn_readfirstlane(tid >> 6);
    int rowbase = blockIdx.x * 64;
    const float* encb = enc + (size_t)rowbase * HH + wv * 256;

    // launder weight bases into VGPRs -> vector loads
    unsigned long long at = (unsigned long long)(Wt + wv * 2048);
    unsigned long long ap = (unsigned long long)(Wp + wv * 2048);
    unsigned long long am = (unsigned long long)(Wm + wv * 2048);
    asm volatile("" : "+v"(at), "+v"(ap), "+v"(am));
    const float* wqt = (const float*)at;
    const float* wqp = (const float*)ap;
    const float* wqm = (const float*)am;

    int srow = lane >> 2;
    int sslot = lane & 3;

    float acc[24];
#pragma unroll
    for (int c = 0; c < 24; ++c) acc[c] = 0.f;

    float4 sreg[4];

#define LOADT(it)                                                             \
    {                                                                         \
        _Pragma("unroll")                                                     \
        for (int j = 0; j < 4; ++j)                                           \
            sreg[j] = *(const float4*)(encb + (size_t)(srow + 16 * j) * HH +  \
                                       (it) * 16 + sslot * 4);                \
    }
#define WRITET(buf)                                                           \
    {                                                                         \
        _Pragma("unroll")                                                     \
        for (int j = 0; j < 4; ++j) {                                         \
            XL(wv, buf, sslot * 4 + 0, srow + 16 * j) = sreg[j].x;            \
            XL(wv, buf, sslot * 4 + 1, srow + 16 * j) = sreg[j].y;            \
            XL(wv, buf, sslot * 4 + 2, srow + 16 * j) = sreg[j].z;            \
            XL(wv, buf, sslot * 4 + 3, srow + 16 * j) = sreg[j].w;            \
        }                                                                     \
    }

    LOADT(0);
    WRITET(0);

    for (int it = 0; it < 16; ++it) {
        int cb = it & 1;
        if (it < 15) LOADT(it + 1);          // issue next tile's global loads early

        const float* pt = wqt + it * 128;
        const float* pp = wqp + it * 128;
        const float* pm = wqm + it * 128;

#pragma unroll 4
        for (int hh = 0; hh < 16; ++hh) {
            float4 t0 = ((const float4*)(pt + hh * 8))[0];
            float4 t1 = ((const float4*)(pt + hh * 8))[1];
            float4 p0 = ((const float4*)(pp + hh * 8))[0];
            float4 p1 = ((const float4*)(pp + hh * 8))[1];
            float4 m0 = ((const float4*)(pm + hh * 8))[0];
            float4 m1 = ((const float4*)(pm + hh * 8))[1];
            float x = XL(wv, cb, hh, lane);
            FMA8(0, t0, t1, x);
            FMA8(8, p0, p1, x);
            FMA8(16, m0, m1, x);
        }
        if (it < 15) WRITET(cb ^ 1);         // write-late, same wave -> no barrier
    }
#undef LOADT
#undef WRITET

    __syncthreads();                          // all waves done reading x tiles
    float* red = smem;                        // overlay: [3][64][25]
    if (wv != 0) {
#pragma unroll
        for (int c = 0; c < 24; ++c) red[((wv - 1) * 64 + lane) * 25 + c] = acc[c];
    }
    __syncthreads();
    if (wv == 0) {
        float s[24];
#pragma unroll
        for (int c = 0; c < 24; ++c)
            s[c] = acc[c] + red[(0 * 64 + lane) * 25 + c]
                          + red[(1 * 64 + lane) * 25 + c]
                          + red[(2 * 64 + lane) * 25 + c];
        size_t row = rowbase + lane;
        float* o0 = out + row * 8;
        float* o1 = out + SEG + row * 8;
        float* o2 = out + 2 * (size_t)SEG + row * 8;
        ((float4*)o0)[0] = make_float4(s[0] + bt[0],  s[1] + bt[1],  s[2] + bt[2],  s[3] + bt[3]);
        ((float4*)o0)[1] = make_float4(s[4] + bt[4],  s[5] + bt[5],  s[6] + bt[6],  s[7] + bt[7]);
        ((float4*)o1)[0] = make_float4(s[8] + bpv[0], s[9] + bpv[1], s[10] + bpv[2], s[11] + bpv[3]);
        ((float4*)o1)[1] = make_float4(s[12] + bpv[4], s[13] + bpv[5], s[14] + bpv[6], s[15] + bpv[7]);
        ((float4*)o2)[0] = make_float4(s[16] + bm[0], s[17] + bm[1], s[18] + bm[2], s[19] + bm[3]);
        ((float4*)o2)[1] = make_float4(s[20] + bm[4], s[21] + bm[5], s[22] + bm[6], s[23] + bm[7]);
    }
}

// ---------------------------------------------------------------------------
// Pure-VALU cross-lane helpers
// ---------------------------------------------------------------------------
#define DPPF(x, ctrl) __int_as_float(__builtin_amdgcn_update_dpp(              \
    0, __float_as_int(x), ctrl, 0xF, 0xF, true))
#define SWIZF(x, pat) __int_as_float(__builtin_amdgcn_ds_swizzle(              \
    __float_as_int(x), pat))
#define BPERMF(a, x)  __int_as_float(__builtin_amdgcn_ds_bpermute(             \
    a, __float_as_int(x)))

__device__ __forceinline__ float rfl(float x) {
    return __int_as_float(__builtin_amdgcn_readfirstlane(__float_as_int(x)));
}

#if __has_builtin(__builtin_amdgcn_permlane16_swap)
__device__ __forceinline__ float xor16f(float x, int lane) {
    typedef unsigned uv2 __attribute__((ext_vector_type(2)));
    uv2 r = __builtin_amdgcn_permlane16_swap(__float_as_uint(x), __float_as_uint(x), false, false);
    return __uint_as_float((lane & 16) ? r.x : r.y);
}
#else
__device__ __forceinline__ float xor16f(float x, int lane) { return SWIZF(x, 0x401F); }
#endif

#if __has_builtin(__builtin_amdgcn_permlane32_swap)
__device__ __forceinline__ float xor32f(float x, int lane) {
    typedef unsigned uv2 __attribute__((ext_vector_type(2)));
    uv2 r = __builtin_amdgcn_permlane32_swap(__float_as_uint(x), __float_as_uint(x), false, false);
    return __uint_as_float((lane & 32) ? r.x : r.y);
}
#else
__device__ __forceinline__ float xor32f(float x, int lane) {
    return BPERMF(((lane ^ 32) << 2), x);
}
#endif

// ---------------------------------------------------------------------------
// Kernel 2: 192 blocks x 128 threads (2 waves). Wave 0: Viterbi (bit-exact
// sequential, ballot argmax, chunked backtrack). Wave 1: CRF logZ in
// multiplicative form (no exp/log on the recurrence chain) + scores.
// One __syncthreads after staging; waves then fully independent.
// ---------------------------------------------------------------------------
__global__ __launch_bounds__(128) void crf_vit(
    const float* __restrict__ logits,
    const int* __restrict__ labels,
    const int* __restrict__ lens,
    const float* __restrict__ trans_t,
    const float* __restrict__ trans_p,
    const float* __restrict__ trans_m,
    float* __restrict__ out_tags,
    float* __restrict__ partial)
{
    __shared__ float llds[TT * KK];        // 16 KB
    __shared__ unsigned bpw[TT * 2];       // 4 KB backpointers (wave-0 private)
    __shared__ unsigned fmapw[64][2];
    __shared__ unsigned char bnd[64];

    int blk = blockIdx.x;
    int h   = blk >> 6;
    int b   = blk & 63;
    int tid = threadIdx.x;
    int wid = __builtin_amdgcn_readfirstlane(tid >> 6);
    int lane = tid & 63;
    int hi = lane >> 3, lo = lane & 7;
    unsigned char* bpb = (unsigned char*)bpw;

    const float* L = logits + ((size_t)h * BATCH + b) * (TT * KK);
    const float4* Lv = (const float4*)L;
    float4* lv = (float4*)llds;
#pragma unroll
    for (int i = 0; i < 8; ++i) lv[tid + 128 * i] = Lv[tid + 128 * i];
    __syncthreads();

    const float* TR = (h == 0) ? trans_t : (h == 1) ? trans_p : trans_m;
    int len = lens[b];
    float trA = TR[lo * 8 + hi];   // even step: kp=lo -> kn=hi
    float trB = TR[hi * 8 + lo];   // odd step:  kp=hi -> kn=lo

    if (wid == 0) {
        // ================= Viterbi wave (bit-exact) =================
        float av = llds[lo];

#define VIT_EVEN(t, LT)                                                        \
    {                                                                          \
        float v0 = av + trA;                                                   \
        float ra = fmaxf(v0, DPPF(v0, 0xB1));                                  \
        float rb = fmaxf(ra, DPPF(ra, 0x4E));                                  \
        float vmax = fmaxf(rb, DPPF(rb, 0x141));                               \
        unsigned long long mk = __ballot(v0 == vmax);                          \
        int vi = __builtin_ctz(((unsigned)(mk >> (lane & 56))) & 0xffu);       \
        if (lo == 0) bpb[(t) * 8 + hi] = (unsigned char)vi;                    \
        av = vmax + (LT);                                                      \
    }
#define VIT_ODD(t, LT)                                                         \
    {                                                                          \
        float v0 = av + trB;                                                   \
        float ra = fmaxf(v0, DPPF(v0, 0x128));                                 \
        float rb = fmaxf(ra, xor16f(ra, lane));                                \
        float vmax = fmaxf(rb, xor32f(rb, lane));                              \
        unsigned long long mk = __ballot(v0 == vmax);                          \
        unsigned long long sel = (mk >> lo) & 0x0101010101010101ULL;           \
        int vi = __builtin_ctzll(sel) >> 3;                                    \
        if (hi == 0) bpb[(t) * 8 + lo] = (unsigned char)vi;                    \
        av = vmax + (LT);                                                      \
    }

        float ltA = llds[8 + hi];
        float ltB = llds[16 + lo];
        for (int t = 1; t <= 509; t += 2) {
            float ltA2 = llds[(t + 2) * 8 + hi];
            int tb = (t + 3 <= 511) ? (t + 3) : 511;
            float ltB2 = llds[tb * 8 + lo];
            VIT_EVEN(t, ltA);
            VIT_ODD(t + 1, ltB);
            ltA = ltA2; ltB = ltB2;
        }
        VIT_EVEN(511, ltA);
#undef VIT_EVEN
#undef VIT_ODD

        // last = argmax of final alpha (hi-indexed, replicated over lo)
        float ra = fmaxf(av, DPPF(av, 0x128));
        float rb = fmaxf(ra, xor16f(ra, lane));
        float vmax = fmaxf(rb, xor32f(rb, lane));
        unsigned long long mk = __ballot(av == vmax);
        int last_ = __builtin_ctzll(mk) >> 3;

        asm volatile("" ::: "memory");  // order bp writes vs reads (same wave)

        // Phase A: lane l composes bp maps for t in [8l+1, 8l+8]
        int t0 = lane * 8;
        unsigned rw[16];
#pragma unroll
        for (int j = 0; j < 8; ++j) {
            int t = t0 + 1 + j;
            if (t <= 511) { rw[2 * j] = bpw[t * 2]; rw[2 * j + 1] = bpw[t * 2 + 1]; }
            else          { rw[2 * j] = 0x03020100u; rw[2 * j + 1] = 0x07060504u; }
        }
        unsigned sv[8];
#pragma unroll
        for (int i = 0; i < 8; ++i) sv[i] = i;
#pragma unroll
        for (int j = 7; j >= 0; --j) {
            unsigned d0 = rw[2 * j], d1 = rw[2 * j + 1];
#pragma unroll
            for (int i = 0; i < 8; ++i) {
                unsigned s = sv[i];
                unsigned d = (s < 4) ? d0 : d1;
                sv[i] = (d >> (8 * (s & 3))) & 0xffu;
            }
        }
        fmapw[lane][0] = sv[0] | (sv[1] << 8) | (sv[2] << 16) | (sv[3] << 24);
        fmapw[lane][1] = sv[4] | (sv[5] << 8) | (sv[6] << 16) | (sv[7] << 24);
        asm volatile("" ::: "memory");

        // Phase B: lane 0 walks 64 chunk maps
        if (lane == 0) {
            unsigned cur = (unsigned)last_;
            for (int l = 63; l >= 0; --l) {
                unsigned d = (cur < 4) ? fmapw[l][0] : fmapw[l][1];
                cur = (d >> (8 * (cur & 3))) & 0xffu;
                bnd[l] = (unsigned char)cur;
            }
        }
        asm volatile("" ::: "memory");

        // Phase C: expand within chunk, write tags
        int off = h * 8;
        float* otag = out_tags + b * (3 * TT) + h * TT;
        unsigned curr = (lane == 63) ? (unsigned)last_ : (unsigned)bnd[lane + 1];
#pragma unroll
        for (int j = 7; j >= 0; --j) {
            unsigned d = (curr < 4) ? rw[2 * j] : rw[2 * j + 1];
            curr = (d >> (8 * (curr & 3))) & 0xffu;
            otag[t0 + j] = (float)((int)curr + off);
        }
    } else {
        // ============ CRF wave: multiplicative logsumexp ============
        // alpha[k] = Mc + log S[k]; S' = (sum_k S[k]*exp(T)) * exp(x - c)
        float EA = __expf(trA);
        float EB = __expf(trB);
        float al0 = llds[lo];
        float c0 = rfl(al0);
        float S = __expf(al0 - c0);
        float Mc = c0;
        float r1 = 0.f, r2 = 0.f, r3 = 0.f;   // stale log(S[0]) pipeline (renorm)
        const float LN8 = 2.0794415416798357f;

#define LSE_EVEN(t, LT)                                                        \
    {                                                                          \
        float c = rfl(LT) + LN8;                                               \
        float F = __expf((LT) - c);                                            \
        float P = S * EA;                                                      \
        float sa = P + DPPF(P, 0xB1);                                          \
        float sb = sa + DPPF(sa, 0x4E);                                        \
        float ss = sb + DPPF(sb, 0x141);                                       \
        if ((t) < len) { S = ss * F; Mc += c; }                                \
        r1 = r2; r2 = r3; r3 = __logf(rfl(S));                                 \
    }
#define LSE_ODD(t, LT)                                                         \
    {                                                                          \
        float c = rfl(LT) + LN8;                                               \
        float F = __expf((LT) - c);                                            \
        float P = S * EB;                                                      \
        float sa = P + DPPF(P, 0x128);                                         \
        float sb = sa + xor16f(sa, lane);                                      \
        float ss = sb + xor32f(sb, lane);                                      \
        if ((t) < len) { S = ss * F; Mc += c; }                                \
        r1 = r2; r2 = r3; r3 = __logf(rfl(S));                                 \
    }

        float ltA = llds[8 + hi];
        float ltB = llds[16 + lo];
        for (int t = 1; t <= 509; t += 2) {
            if ((t & 3) == 1) {               // exact-bookkeeping renorm, every 4 steps
                float g = r2;                 // stale log S[0] (any exact value valid)
                S *= __expf(-g);
                Mc += g;
            }
            float ltA2 = llds[(t + 2) * 8 + hi];
            int tb = (t + 3 <= 511) ? (t + 3) : 511;
            float ltB2 = llds[tb * 8 + lo];
            LSE_EVEN(t, ltA);
            LSE_ODD(t + 1, ltB);
            ltA = ltA2; ltB = ltB2;
        }
        LSE_EVEN(511, ltA);
#undef LSE_EVEN
#undef LSE_ODD

        // logZ = LSE over hi field of (Mc + log S)
        float aj = Mc + __logf(S);
        float za = fmaxf(aj, DPPF(aj, 0x128));
        float zb = fmaxf(za, xor16f(za, lane));
        float zmax = fmaxf(zb, xor32f(zb, lane));
        float ze = __expf(aj - zmax);
        float zs = ze + DPPF(ze, 0x128);
        float zs2 = zs + xor16f(zs, lane);
        float zsum = zs2 + xor32f(zs2, lane);
        float logZ = zmax + __logf(zsum);

        // emit + transition scores (lane-parallel over t)
        const int* lab = labels + b * (3 * TT) + h * TT;
        int off = h * 8;
        float sc = 0.f;
#pragma unroll
        for (int j = 0; j < 8; ++j) {
            int t = lane + 64 * j;
            if (t < len) {
                int tg = lab[t] - off;
                sc += llds[t * 8 + tg];
                if (t >= 1) {
                    int tp = lab[t - 1] - off;
                    sc += TR[tp * 8 + tg];
                }
            }
        }
#pragma unroll
        for (int d = 1; d <= 32; d <<= 1) sc += __shfl_xor(sc, d);

        if (lane == 0) partial[blk] = logZ - sc;
    }
}

// ---------------------------------------------------------------------------
// Kernel 3: deterministic loss reduction (192 partials -> scalar)
// ---------------------------------------------------------------------------
__global__ __launch_bounds__(64) void loss_reduce(
    const float* __restrict__ partial, float* __restrict__ out_loss)
{
    int lane = threadIdx.x;
    float s = partial[lane] + partial[lane + 64] + partial[lane + 128];
#pragma unroll
    for (int d = 1; d <= 32; d <<= 1) s += __shfl_xor(s, d);
    if (lane == 0) *out_loss = s;
}

// ---------------------------------------------------------------------------
extern "C" void kernel_launch(void* const* d_in, const int* in_sizes, int n_in,
                              void* d_out, int out_size, void* d_ws, size_t ws_size,
                              hipStream_t stream) {
    const float* enc    = (const float*)d_in[0];
    const int*   labels = (const int*)d_in[1];
    const int*   lens   = (const int*)d_in[2];
    const float* Wt     = (const float*)d_in[3];
    const float* bt     = (const float*)d_in[4];
    const float* Wp     = (const float*)d_in[5];
    const float* bpv    = (const float*)d_in[6];
    const float* Wm     = (const float*)d_in[7];
    const float* bm     = (const float*)d_in[8];
    const float* tr_t   = (const float*)d_in[9];
    const float* tr_p   = (const float*)d_in[10];
    const float* tr_m   = (const float*)d_in[11];

    float* out = (float*)d_out;
    float* partial = (float*)d_ws;   // 192 floats

    gemm_heads<<<ROWS / 64, 256, 0, stream>>>(enc, Wt, bt, Wp, bpv, Wm, bm, out);
    crf_vit<<<192, 128, 0, stream>>>(out, labels, lens, tr_t, tr_p, tr_m,
                                     out + TAGS_OFF, partial);
    loss_reduce<<<1, 64, 0, stream>>>(partial, out + LOSS_OFF);
}

// Round 6
// 166.514 us; speedup vs baseline: 1.2386x; 1.2386x over previous
//
#include <hip/hip_runtime.h>
#include <hip/hip_bf16.h>
#include <math.h>

#define BATCH 64
#define TT 512
#define HH 1024
#define KK 8
#define ROWS (BATCH * TT)          // 32768
#define SEG  (ROWS * KK)           // 262144 floats per logits output
#define TAGS_OFF (3 * SEG)         // 786432
#define LOSS_OFF (TAGS_OFF + BATCH * 3 * TT)  // 884736

#define FMA8(base, w0, w1, xe)                          \
    acc[base + 0] = fmaf(xe, w0.x, acc[base + 0]);      \
    acc[base + 1] = fmaf(xe, w0.y, acc[base + 1]);      \
    acc[base + 2] = fmaf(xe, w0.z, acc[base + 2]);      \
    acc[base + 3] = fmaf(xe, w0.w, acc[base + 3]);      \
    acc[base + 4] = fmaf(xe, w1.x, acc[base + 4]);      \
    acc[base + 5] = fmaf(xe, w1.y, acc[base + 5]);      \
    acc[base + 6] = fmaf(xe, w1.z, acc[base + 6]);      \
    acc[base + 7] = fmaf(xe, w1.w, acc[base + 7]);

#define FMA24(W, xe)                                    \
    FMA8(0,  W[0], W[1], xe)                            \
    FMA8(8,  W[2], W[3], xe)                            \
    FMA8(16, W[4], W[5], xe)

// ---------------------------------------------------------------------------
// Kernel 1: fused 3-head GEMM. 512 blocks x 4 waves, K-quarter per wave,
// per-wave private double-buffered enc staging (LDS transposed tiles).
// Weights: explicit 4-buffer 2-deep register pipeline of laundered VECTOR
// loads (vmcnt pipe, disjoint from the LDS lgkm pipe). All buffer indices
// compile-time static (rule #20) so they live in VGPRs.
// ---------------------------------------------------------------------------
#define XL(wv, buf, hh, col) smem[(((wv) * 2 + (buf)) * 16 + (hh)) * 68 + (col)]

__global__ __launch_bounds__(256, 2) void gemm_heads(
    const float* __restrict__ enc,
    const float* __restrict__ Wt, const float* __restrict__ bt,
    const float* __restrict__ Wp, const float* __restrict__ bpv,
    const float* __restrict__ Wm, const float* __restrict__ bm,
    float* __restrict__ out)
{
    __shared__ float smem[4 * 2 * 16 * 68];   // 34.8 KB; red overlays after sync

    int tid  = threadIdx.x;
    int lane = tid & 63;
    int wv   = __builtin_amdgcn_readfirstlane(tid >> 6);
    int rowbase = blockIdx.x * 64;
    const float* encb = enc + (size_t)rowbase * HH + wv * 256;

    // launder weight bases into VGPRs -> vector loads (vmcnt, not s_load/lgkm)
    unsigned long long at = (unsigned long long)(Wt + wv * 2048);
    unsigned long long ap = (unsigned long long)(Wp + wv * 2048);
    unsigned long long am = (unsigned long long)(Wm + wv * 2048);
    asm volatile("" : "+v"(at), "+v"(ap), "+v"(am));
    const float* wqt = (const float*)at;
    const float* wqp = (const float*)ap;
    const float* wqm = (const float*)am;

    int srow = lane >> 2;
    int sslot = lane & 3;

    float acc[24];
#pragma unroll
    for (int c = 0; c < 24; ++c) acc[c] = 0.f;

    float4 sreg[4];

#define LOADT(it)                                                             \
    {                                                                         \
        _Pragma("unroll")                                                     \
        for (int j = 0; j < 4; ++j)                                           \
            sreg[j] = *(const float4*)(encb + (size_t)(srow + 16 * j) * HH +  \
                                       (it) * 16 + sslot * 4);                \
    }
#define WRITET(buf)                                                           \
    {                                                                         \
        _Pragma("unroll")                                                     \
        for (int j = 0; j < 4; ++j) {                                         \
            XL(wv, buf, sslot * 4 + 0, srow + 16 * j) = sreg[j].x;            \
            XL(wv, buf, sslot * 4 + 1, srow + 16 * j) = sreg[j].y;            \
            XL(wv, buf, sslot * 4 + 2, srow + 16 * j) = sreg[j].z;            \
            XL(wv, buf, sslot * 4 + 3, srow + 16 * j) = sreg[j].w;            \
        }                                                                     \
    }
#define WLOAD(dst, hglob)                                                     \
    {                                                                         \
        const float* pt_ = wqt + (size_t)(hglob) * 8;                         \
        const float* pp_ = wqp + (size_t)(hglob) * 8;                         \
        const float* pm_ = wqm + (size_t)(hglob) * 8;                         \
        dst[0] = ((const float4*)pt_)[0]; dst[1] = ((const float4*)pt_)[1];   \
        dst[2] = ((const float4*)pp_)[0]; dst[3] = ((const float4*)pp_)[1];   \
        dst[4] = ((const float4*)pm_)[0]; dst[5] = ((const float4*)pm_)[1];   \
    }

    float4 w0[6], w1[6], w2[6], w3[6];
    WLOAD(w0, 0)
    WLOAD(w1, 1)
    LOADT(0)
    WRITET(0)

    // stage hs computes buf[hs&3] (holds weights for h=hs) and loads h=hs+2
    // into buf[(hs+2)&3] (freed two stages ago): 2-deep prefetch.
    for (int it = 0; it < 15; ++it) {
        int cb = it & 1;
        LOADT(it + 1)                          // next enc tile (early issue)
#pragma unroll
        for (int hh = 0; hh < 16; ++hh) {
            int hl = it * 16 + hh;             // = hs; hl+2 <= 241 < 256 (safe)
            float x = XL(wv, cb, hh, lane);
            switch (hh & 3) {
            case 0: WLOAD(w2, hl + 2) FMA24(w0, x) break;
            case 1: WLOAD(w3, hl + 2) FMA24(w1, x) break;
            case 2: WLOAD(w0, hl + 2) FMA24(w2, x) break;
            case 3: WLOAD(w1, hl + 2) FMA24(w3, x) break;
            }
        }
        WRITET(cb ^ 1)                         // write-late; same wave, no barrier
    }
    // peeled it = 15 (cb = 1): prefetch only while hl+2 <= 255
    {
#pragma unroll
        for (int hh = 0; hh < 14; ++hh) {
            float x = XL(wv, 1, hh, lane);
            switch (hh & 3) {
            case 0: WLOAD(w2, 242 + hh) FMA24(w0, x) break;
            case 1: WLOAD(w3, 242 + hh) FMA24(w1, x) break;
            case 2: WLOAD(w0, 242 + hh) FMA24(w2, x) break;
            case 3: WLOAD(w1, 242 + hh) FMA24(w3, x) break;
            }
        }
        float x = XL(wv, 1, 14, lane);
        FMA24(w2, x)                            // hs=254 -> buf 254&3=2
        x = XL(wv, 1, 15, lane);
        FMA24(w3, x)                            // hs=255 -> buf 3
    }
#undef LOADT
#undef WRITET
#undef WLOAD

    __syncthreads();                          // all waves done reading x tiles
    float* red = smem;                        // overlay: [3][64][25]
    if (wv != 0) {
#pragma unroll
        for (int c = 0; c < 24; ++c) red[((wv - 1) * 64 + lane) * 25 + c] = acc[c];
    }
    __syncthreads();
    if (wv == 0) {
        float s[24];
#pragma unroll
        for (int c = 0; c < 24; ++c)
            s[c] = acc[c] + red[(0 * 64 + lane) * 25 + c]
                          + red[(1 * 64 + lane) * 25 + c]
                          + red[(2 * 64 + lane) * 25 + c];
        size_t row = rowbase + lane;
        float* o0 = out + row * 8;
        float* o1 = out + SEG + row * 8;
        float* o2 = out + 2 * (size_t)SEG + row * 8;
        ((float4*)o0)[0] = make_float4(s[0] + bt[0],  s[1] + bt[1],  s[2] + bt[2],  s[3] + bt[3]);
        ((float4*)o0)[1] = make_float4(s[4] + bt[4],  s[5] + bt[5],  s[6] + bt[6],  s[7] + bt[7]);
        ((float4*)o1)[0] = make_float4(s[8] + bpv[0], s[9] + bpv[1], s[10] + bpv[2], s[11] + bpv[3]);
        ((float4*)o1)[1] = make_float4(s[12] + bpv[4], s[13] + bpv[5], s[14] + bpv[6], s[15] + bpv[7]);
        ((float4*)o2)[0] = make_float4(s[16] + bm[0], s[17] + bm[1], s[18] + bm[2], s[19] + bm[3]);
        ((float4*)o2)[1] = make_float4(s[20] + bm[4], s[21] + bm[5], s[22] + bm[6], s[23] + bm[7]);
    }
}

// ---------------------------------------------------------------------------
// Pure-VALU cross-lane helpers
// ---------------------------------------------------------------------------
#define DPPF(x, ctrl) __int_as_float(__builtin_amdgcn_update_dpp(              \
    0, __float_as_int(x), ctrl, 0xF, 0xF, true))
#define SWIZF(x, pat) __int_as_float(__builtin_amdgcn_ds_swizzle(              \
    __float_as_int(x), pat))
#define BPERMF(a, x)  __int_as_float(__builtin_amdgcn_ds_bpermute(             \
    a, __float_as_int(x)))

__device__ __forceinline__ float rfl(float x) {
    return __int_as_float(__builtin_amdgcn_readfirstlane(__float_as_int(x)));
}

#if __has_builtin(__builtin_amdgcn_permlane16_swap)
__device__ __forceinline__ float xor16f(float x, int lane) {
    typedef unsigned uv2 __attribute__((ext_vector_type(2)));
    uv2 r = __builtin_amdgcn_permlane16_swap(__float_as_uint(x), __float_as_uint(x), false, false);
    return __uint_as_float((lane & 16) ? r.x : r.y);
}
#else
__device__ __forceinline__ float xor16f(float x, int lane) { return SWIZF(x, 0x401F); }
#endif

#if __has_builtin(__builtin_amdgcn_permlane32_swap)
__device__ __forceinline__ float xor32f(float x, int lane) {
    typedef unsigned uv2 __attribute__((ext_vector_type(2)));
    uv2 r = __builtin_amdgcn_permlane32_swap(__float_as_uint(x), __float_as_uint(x), false, false);
    return __uint_as_float((lane & 32) ? r.x : r.y);
}
#else
__device__ __forceinline__ float xor32f(float x, int lane) {
    return BPERMF(((lane ^ 32) << 2), x);
}
#endif

// ---------------------------------------------------------------------------
// Kernel 2: 192 blocks x 128 threads (2 waves). Wave 0: Viterbi (bit-exact,
// ballot argmax, chunked backtrack). Wave 1: CRF logZ in multiplicative form
// (no exp/log on the recurrence chain) + scores. (R5 version, proven.)
// ---------------------------------------------------------------------------
__global__ __launch_bounds__(128) void crf_vit(
    const float* __restrict__ logits,
    const int* __restrict__ labels,
    const int* __restrict__ lens,
    const float* __restrict__ trans_t,
    const float* __restrict__ trans_p,
    const float* __restrict__ trans_m,
    float* __restrict__ out_tags,
    float* __restrict__ partial)
{
    __shared__ float llds[TT * KK];        // 16 KB
    __shared__ unsigned bpw[TT * 2];       // 4 KB backpointers (wave-0 private)
    __shared__ unsigned fmapw[64][2];
    __shared__ unsigned char bnd[64];

    int blk = blockIdx.x;
    int h   = blk >> 6;
    int b   = blk & 63;
    int tid = threadIdx.x;
    int wid = __builtin_amdgcn_readfirstlane(tid >> 6);
    int lane = tid & 63;
    int hi = lane >> 3, lo = lane & 7;
    unsigned char* bpb = (unsigned char*)bpw;

    const float* L = logits + ((size_t)h * BATCH + b) * (TT * KK);
    const float4* Lv = (const float4*)L;
    float4* lv = (float4*)llds;
#pragma unroll
    for (int i = 0; i < 8; ++i) lv[tid + 128 * i] = Lv[tid + 128 * i];
    __syncthreads();

    const float* TR = (h == 0) ? trans_t : (h == 1) ? trans_p : trans_m;
    int len = lens[b];
    float trA = TR[lo * 8 + hi];   // even step: kp=lo -> kn=hi
    float trB = TR[hi * 8 + lo];   // odd step:  kp=hi -> kn=lo

    if (wid == 0) {
        // ================= Viterbi wave (bit-exact) =================
        float av = llds[lo];

#define VIT_EVEN(t, LT)                                                        \
    {                                                                          \
        float v0 = av + trA;                                                   \
        float ra = fmaxf(v0, DPPF(v0, 0xB1));                                  \
        float rb = fmaxf(ra, DPPF(ra, 0x4E));                                  \
        float vmax = fmaxf(rb, DPPF(rb, 0x141));                               \
        unsigned long long mk = __ballot(v0 == vmax);                          \
        int vi = __builtin_ctz(((unsigned)(mk >> (lane & 56))) & 0xffu);       \
        if (lo == 0) bpb[(t) * 8 + hi] = (unsigned char)vi;                    \
        av = vmax + (LT);                                                      \
    }
#define VIT_ODD(t, LT)                                                         \
    {                                                                          \
        float v0 = av + trB;                                                   \
        float ra = fmaxf(v0, DPPF(v0, 0x128));                                 \
        float rb = fmaxf(ra, xor16f(ra, lane));                                \
        float vmax = fmaxf(rb, xor32f(rb, lane));                              \
        unsigned long long mk = __ballot(v0 == vmax);                          \
        unsigned long long sel = (mk >> lo) & 0x0101010101010101ULL;           \
        int vi = __builtin_ctzll(sel) >> 3;                                    \
        if (hi == 0) bpb[(t) * 8 + lo] = (unsigned char)vi;                    \
        av = vmax + (LT);                                                      \
    }

        float ltA = llds[8 + hi];
        float ltB = llds[16 + lo];
        for (int t = 1; t <= 509; t += 2) {
            float ltA2 = llds[(t + 2) * 8 + hi];
            int tb = (t + 3 <= 511) ? (t + 3) : 511;
            float ltB2 = llds[tb * 8 + lo];
            VIT_EVEN(t, ltA);
            VIT_ODD(t + 1, ltB);
            ltA = ltA2; ltB = ltB2;
        }
        VIT_EVEN(511, ltA);
#undef VIT_EVEN
#undef VIT_ODD

        float ra = fmaxf(av, DPPF(av, 0x128));
        float rb = fmaxf(ra, xor16f(ra, lane));
        float vmax = fmaxf(rb, xor32f(rb, lane));
        unsigned long long mk = __ballot(av == vmax);
        int last_ = __builtin_ctzll(mk) >> 3;

        asm volatile("" ::: "memory");

        // Phase A: lane l composes bp maps for t in [8l+1, 8l+8]
        int t0 = lane * 8;
        unsigned rw[16];
#pragma unroll
        for (int j = 0; j < 8; ++j) {
            int t = t0 + 1 + j;
            if (t <= 511) { rw[2 * j] = bpw[t * 2]; rw[2 * j + 1] = bpw[t * 2 + 1]; }
            else          { rw[2 * j] = 0x03020100u; rw[2 * j + 1] = 0x07060504u; }
        }
        unsigned sv[8];
#pragma unroll
        for (int i = 0; i < 8; ++i) sv[i] = i;
#pragma unroll
        for (int j = 7; j >= 0; --j) {
            unsigned d0 = rw[2 * j], d1 = rw[2 * j + 1];
#pragma unroll
            for (int i = 0; i < 8; ++i) {
                unsigned s = sv[i];
                unsigned d = (s < 4) ? d0 : d1;
                sv[i] = (d >> (8 * (s & 3))) & 0xffu;
            }
        }
        fmapw[lane][0] = sv[0] | (sv[1] << 8) | (sv[2] << 16) | (sv[3] << 24);
        fmapw[lane][1] = sv[4] | (sv[5] << 8) | (sv[6] << 16) | (sv[7] << 24);
        asm volatile("" ::: "memory");

        if (lane == 0) {
            unsigned cur = (unsigned)last_;
            for (int l = 63; l >= 0; --l) {
                unsigned d = (cur < 4) ? fmapw[l][0] : fmapw[l][1];
                cur = (d >> (8 * (cur & 3))) & 0xffu;
                bnd[l] = (unsigned char)cur;
            }
        }
        asm volatile("" ::: "memory");

        int off = h * 8;
        float* otag = out_tags + b * (3 * TT) + h * TT;
        unsigned curr = (lane == 63) ? (unsigned)last_ : (unsigned)bnd[lane + 1];
#pragma unroll
        for (int j = 7; j >= 0; --j) {
            unsigned d = (curr < 4) ? rw[2 * j] : rw[2 * j + 1];
            curr = (d >> (8 * (curr & 3))) & 0xffu;
            otag[t0 + j] = (float)((int)curr + off);
        }
    } else {
        // ============ CRF wave: multiplicative logsumexp ============
        float EA = __expf(trA);
        float EB = __expf(trB);
        float al0 = llds[lo];
        float c0 = rfl(al0);
        float S = __expf(al0 - c0);
        float Mc = c0;
        float r1 = 0.f, r2 = 0.f, r3 = 0.f;
        const float LN8 = 2.0794415416798357f;

#define LSE_EVEN(t, LT)                                                        \
    {                                                                          \
        float c = rfl(LT) + LN8;                                               \
        float F = __expf((LT) - c);                                            \
        float P = S * EA;                                                      \
        float sa = P + DPPF(P, 0xB1);                                          \
        float sb = sa + DPPF(sa, 0x4E);                                        \
        float ss = sb + DPPF(sb, 0x141);                                       \
        if ((t) < len) { S = ss * F; Mc += c; }                                \
        r1 = r2; r2 = r3; r3 = __logf(rfl(S));                                 \
    }
#define LSE_ODD(t, LT)                                                         \
    {                                                                          \
        float c = rfl(LT) + LN8;                                               \
        float F = __expf((LT) - c);                                            \
        float P = S * EB;                                                      \
        float sa = P + DPPF(P, 0x128);                                         \
        float sb = sa + xor16f(sa, lane);                                      \
        float ss = sb + xor32f(sb, lane);                                      \
        if ((t) < len) { S = ss * F; Mc += c; }                                \
        r1 = r2; r2 = r3; r3 = __logf(rfl(S));                                 \
    }

        float ltA = llds[8 + hi];
        float ltB = llds[16 + lo];
        for (int t = 1; t <= 509; t += 2) {
            if ((t & 3) == 1) {
                float g = r2;
                S *= __expf(-g);
                Mc += g;
            }
            float ltA2 = llds[(t + 2) * 8 + hi];
            int tb = (t + 3 <= 511) ? (t + 3) : 511;
            float ltB2 = llds[tb * 8 + lo];
            LSE_EVEN(t, ltA);
            LSE_ODD(t + 1, ltB);
            ltA = ltA2; ltB = ltB2;
        }
        LSE_EVEN(511, ltA);
#undef LSE_EVEN
#undef LSE_ODD

        float aj = Mc + __logf(S);
        float za = fmaxf(aj, DPPF(aj, 0x128));
        float zb = fmaxf(za, xor16f(za, lane));
        float zmax = fmaxf(zb, xor32f(zb, lane));
        float ze = __expf(aj - zmax);
        float zs = ze + DPPF(ze, 0x128);
        float zs2 = zs + xor16f(zs, lane);
        float zsum = zs2 + xor32f(zs2, lane);
        float logZ = zmax + __logf(zsum);

        const int* lab = labels + b * (3 * TT) + h * TT;
        int off = h * 8;
        float sc = 0.f;
#pragma unroll
        for (int j = 0; j < 8; ++j) {
            int t = lane + 64 * j;
            if (t < len) {
                int tg = lab[t] - off;
                sc += llds[t * 8 + tg];
                if (t >= 1) {
                    int tp = lab[t - 1] - off;
                    sc += TR[tp * 8 + tg];
                }
            }
        }
#pragma unroll
        for (int d = 1; d <= 32; d <<= 1) sc += __shfl_xor(sc, d);

        if (lane == 0) partial[blk] = logZ - sc;
    }
}

// ---------------------------------------------------------------------------
// Kernel 3: deterministic loss reduction (192 partials -> scalar)
// ---------------------------------------------------------------------------
__global__ __launch_bounds__(64) void loss_reduce(
    const float* __restrict__ partial, float* __restrict__ out_loss)
{
    int lane = threadIdx.x;
    float s = partial[lane] + partial[lane + 64] + partial[lane + 128];
#pragma unroll
    for (int d = 1; d <= 32; d <<= 1) s += __shfl_xor(s, d);
    if (lane == 0) *out_loss = s;
}

// ---------------------------------------------------------------------------
extern "C" void kernel_launch(void* const* d_in, const int* in_sizes, int n_in,
                              void* d_out, int out_size, void* d_ws, size_t ws_size,
                              hipStream_t stream) {
    const float* enc    = (const float*)d_in[0];
    const int*   labels = (const int*)d_in[1];
    const int*   lens   = (const int*)d_in[2];
    const float* Wt     = (const float*)d_in[3];
    const float* bt     = (const float*)d_in[4];
    const float* Wp     = (const float*)d_in[5];
    const float* bpv    = (const float*)d_in[6];
    const float* Wm     = (const float*)d_in[7];
    const float* bm     = (const float*)d_in[8];
    const float* tr_t   = (const float*)d_in[9];
    const float* tr_p   = (const float*)d_in[10];
    const float* tr_m   = (const float*)d_in[11];

    float* out = (float*)d_out;
    float* partial = (float*)d_ws;   // 192 floats

    gemm_heads<<<ROWS / 64, 256, 0, stream>>>(enc, Wt, bt, Wp, bpv, Wm, bm, out);
    crf_vit<<<192, 128, 0, stream>>>(out, labels, lens, tr_t, tr_p, tr_m,
                                     out + TAGS_OFF, partial);
    loss_reduce<<<1, 64, 0, stream>>>(partial, out + LOSS_OFF);
}

// Round 7
// 94.945 us; speedup vs baseline: 2.1723x; 1.7538x over previous
//
#include <hip/hip_runtime.h>
#include <hip/hip_bf16.h>
#include <math.h>

#define BATCH 64
#define TT 512
#define HH 1024
#define KK 8
#define ROWS (BATCH * TT)          // 32768
#define SEG  (ROWS * KK)           // 262144 floats per logits output
#define TAGS_OFF (3 * SEG)         // 786432
#define LOSS_OFF (TAGS_OFF + BATCH * 3 * TT)  // 884736

#define FMA8(base, w0, w1, xe)                          \
    acc[base + 0] = fmaf(xe, w0.x, acc[base + 0]);      \
    acc[base + 1] = fmaf(xe, w0.y, acc[base + 1]);      \
    acc[base + 2] = fmaf(xe, w0.z, acc[base + 2]);      \
    acc[base + 3] = fmaf(xe, w0.w, acc[base + 3]);      \
    acc[base + 4] = fmaf(xe, w1.x, acc[base + 4]);      \
    acc[base + 5] = fmaf(xe, w1.y, acc[base + 5]);      \
    acc[base + 6] = fmaf(xe, w1.z, acc[base + 6]);      \
    acc[base + 7] = fmaf(xe, w1.w, acc[base + 7]);

// ---------------------------------------------------------------------------
// Kernel 1: fused 3-head GEMM. 512 blocks x 4 waves, K-quarter per wave,
// per-wave private double-buffered staging of BOTH x (transposed tile) AND
// weights into LDS. Weight reads in the compute loop are wave-uniform
// ds_read_b128 -> HW broadcast (conflict-free), on the DS pipe (no VALU
// contention, short lgkm latency the compiler schedules well). This removes
// the per-lane global weight loads whose scheduling the compiler kept
// serializing (R4: s_load drain; R5/R6: sunk vector loads).
// ---------------------------------------------------------------------------
#define XL(wv, buf, hh, col) smem[(((wv) * 2 + (buf)) * 16 + (hh)) * 68 + (col)]

__global__ __launch_bounds__(256, 2) void gemm_heads(
    const float* __restrict__ enc,
    const float* __restrict__ Wt, const float* __restrict__ bt,
    const float* __restrict__ Wp, const float* __restrict__ bpv,
    const float* __restrict__ Wm, const float* __restrict__ bm,
    float* __restrict__ out)
{
    __shared__ float smem[4 * 2 * 16 * 68];   // 34.8 KB x tiles; red overlays
    __shared__ float wl[4][2][16][24];        // 12.3 KB weight tiles

    int tid  = threadIdx.x;
    int lane = tid & 63;
    int wv   = __builtin_amdgcn_readfirstlane(tid >> 6);
    int rowbase = blockIdx.x * 64;
    const float* encb = enc + (size_t)rowbase * HH + wv * 256;
    const float* Wqt = Wt + wv * 2048;        // quarter base: 256 rows x 8
    const float* Wqp = Wp + wv * 2048;
    const float* Wqm = Wm + wv * 2048;

    int srow = lane >> 2;
    int sslot = lane & 3;
    int wrow = lane >> 3;        // weight LDS row (0..7), +8 for second word
    int wcol = lane & 7;

    float acc[24];
#pragma unroll
    for (int c = 0; c < 24; ++c) acc[c] = 0.f;

    float4 sreg[4];
    float  wreg[6];

#define LOADT(it)                                                             \
    {                                                                         \
        _Pragma("unroll")                                                     \
        for (int j = 0; j < 4; ++j)                                           \
            sreg[j] = *(const float4*)(encb + (size_t)(srow + 16 * j) * HH +  \
                                       (it) * 16 + sslot * 4);                \
    }
#define WRITET(buf)                                                           \
    {                                                                         \
        _Pragma("unroll")                                                     \
        for (int j = 0; j < 4; ++j) {                                         \
            XL(wv, buf, sslot * 4 + 0, srow + 16 * j) = sreg[j].x;            \
            XL(wv, buf, sslot * 4 + 1, srow + 16 * j) = sreg[j].y;            \
            XL(wv, buf, sslot * 4 + 2, srow + 16 * j) = sreg[j].z;            \
            XL(wv, buf, sslot * 4 + 3, srow + 16 * j) = sreg[j].w;            \
        }                                                                     \
    }
// per it-tile: 384 floats (16h x 24 outputs); lane loads word `lane` and
// `lane+64` of each head's 128-float contiguous tile -> fully coalesced.
#define WLOADG(it)                                                            \
    {                                                                         \
        const float* pt_ = Wqt + (it) * 128;                                  \
        const float* pp_ = Wqp + (it) * 128;                                  \
        const float* pm_ = Wqm + (it) * 128;                                  \
        wreg[0] = pt_[lane]; wreg[1] = pt_[64 + lane];                        \
        wreg[2] = pp_[lane]; wreg[3] = pp_[64 + lane];                        \
        wreg[4] = pm_[lane]; wreg[5] = pm_[64 + lane];                        \
    }
// word g of a head tile (g = hh*8+c) -> wl[..][hh][off+c]; g=lane and lane+64
#define WWRITE(buf)                                                           \
    {                                                                         \
        wl[wv][buf][wrow][wcol]          = wreg[0];                           \
        wl[wv][buf][8 + wrow][wcol]      = wreg[1];                           \
        wl[wv][buf][wrow][8 + wcol]      = wreg[2];                           \
        wl[wv][buf][8 + wrow][8 + wcol]  = wreg[3];                           \
        wl[wv][buf][wrow][16 + wcol]     = wreg[4];                           \
        wl[wv][buf][8 + wrow][16 + wcol] = wreg[5];                           \
    }

    LOADT(0)
    WLOADG(0)
    WRITET(0)
    WWRITE(0)

    for (int it = 0; it < 16; ++it) {
        int cb = it & 1;
        if (it < 15) {                        // issue next tile's loads early
            LOADT(it + 1)
            WLOADG(it + 1)
        }
#pragma unroll
        for (int hh = 0; hh < 16; ++hh) {
            float x = XL(wv, cb, hh, lane);
            const float* wp_ = &wl[wv][cb][hh][0];   // wave-uniform -> broadcast
            float4 t0 = ((const float4*)wp_)[0];
            float4 t1 = ((const float4*)wp_)[1];
            float4 p0 = ((const float4*)wp_)[2];
            float4 p1 = ((const float4*)wp_)[3];
            float4 m0 = ((const float4*)wp_)[4];
            float4 m1 = ((const float4*)wp_)[5];
            FMA8(0, t0, t1, x);
            FMA8(8, p0, p1, x);
            FMA8(16, m0, m1, x);
        }
        if (it < 15) {                        // write-late; per-wave private
            WRITET(cb ^ 1)
            WWRITE(cb ^ 1)
        }
    }
#undef LOADT
#undef WRITET
#undef WLOADG
#undef WWRITE

    __syncthreads();                          // all waves done with x tiles
    float* red = smem;                        // overlay: [3][64][25]
    if (wv != 0) {
#pragma unroll
        for (int c = 0; c < 24; ++c) red[((wv - 1) * 64 + lane) * 25 + c] = acc[c];
    }
    __syncthreads();
    if (wv == 0) {
        float s[24];
#pragma unroll
        for (int c = 0; c < 24; ++c)
            s[c] = acc[c] + red[(0 * 64 + lane) * 25 + c]
                          + red[(1 * 64 + lane) * 25 + c]
                          + red[(2 * 64 + lane) * 25 + c];
        size_t row = rowbase + lane;
        float* o0 = out + row * 8;
        float* o1 = out + SEG + row * 8;
        float* o2 = out + 2 * (size_t)SEG + row * 8;
        ((float4*)o0)[0] = make_float4(s[0] + bt[0],  s[1] + bt[1],  s[2] + bt[2],  s[3] + bt[3]);
        ((float4*)o0)[1] = make_float4(s[4] + bt[4],  s[5] + bt[5],  s[6] + bt[6],  s[7] + bt[7]);
        ((float4*)o1)[0] = make_float4(s[8] + bpv[0], s[9] + bpv[1], s[10] + bpv[2], s[11] + bpv[3]);
        ((float4*)o1)[1] = make_float4(s[12] + bpv[4], s[13] + bpv[5], s[14] + bpv[6], s[15] + bpv[7]);
        ((float4*)o2)[0] = make_float4(s[16] + bm[0], s[17] + bm[1], s[18] + bm[2], s[19] + bm[3]);
        ((float4*)o2)[1] = make_float4(s[20] + bm[4], s[21] + bm[5], s[22] + bm[6], s[23] + bm[7]);
    }
}

// ---------------------------------------------------------------------------
// Pure-VALU cross-lane helpers
// ---------------------------------------------------------------------------
#define DPPF(x, ctrl) __int_as_float(__builtin_amdgcn_update_dpp(              \
    0, __float_as_int(x), ctrl, 0xF, 0xF, true))
#define SWIZF(x, pat) __int_as_float(__builtin_amdgcn_ds_swizzle(              \
    __float_as_int(x), pat))
#define BPERMF(a, x)  __int_as_float(__builtin_amdgcn_ds_bpermute(             \
    a, __float_as_int(x)))

__device__ __forceinline__ float rfl(float x) {
    return __int_as_float(__builtin_amdgcn_readfirstlane(__float_as_int(x)));
}

#if __has_builtin(__builtin_amdgcn_permlane16_swap)
__device__ __forceinline__ float xor16f(float x, int lane) {
    typedef unsigned uv2 __attribute__((ext_vector_type(2)));
    uv2 r = __builtin_amdgcn_permlane16_swap(__float_as_uint(x), __float_as_uint(x), false, false);
    return __uint_as_float((lane & 16) ? r.x : r.y);
}
#else
__device__ __forceinline__ float xor16f(float x, int lane) { return SWIZF(x, 0x401F); }
#endif

#if __has_builtin(__builtin_amdgcn_permlane32_swap)
__device__ __forceinline__ float xor32f(float x, int lane) {
    typedef unsigned uv2 __attribute__((ext_vector_type(2)));
    uv2 r = __builtin_amdgcn_permlane32_swap(__float_as_uint(x), __float_as_uint(x), false, false);
    return __uint_as_float((lane & 32) ? r.x : r.y);
}
#else
__device__ __forceinline__ float xor32f(float x, int lane) {
    return BPERMF(((lane ^ 32) << 2), x);
}
#endif

// ---------------------------------------------------------------------------
// Kernel 2: 192 blocks x 128 threads (2 waves). Wave 0: Viterbi (bit-exact,
// ballot argmax, chunked backtrack). Wave 1: CRF logZ in multiplicative form
// (no exp/log on the recurrence chain) + scores. (R5/R6 version, proven.)
// ---------------------------------------------------------------------------
__global__ __launch_bounds__(128) void crf_vit(
    const float* __restrict__ logits,
    const int* __restrict__ labels,
    const int* __restrict__ lens,
    const float* __restrict__ trans_t,
    const float* __restrict__ trans_p,
    const float* __restrict__ trans_m,
    float* __restrict__ out_tags,
    float* __restrict__ partial)
{
    __shared__ float llds[TT * KK];        // 16 KB
    __shared__ unsigned bpw[TT * 2];       // 4 KB backpointers (wave-0 private)
    __shared__ unsigned fmapw[64][2];
    __shared__ unsigned char bnd[64];

    int blk = blockIdx.x;
    int h   = blk >> 6;
    int b   = blk & 63;
    int tid = threadIdx.x;
    int wid = __builtin_amdgcn_readfirstlane(tid >> 6);
    int lane = tid & 63;
    int hi = lane >> 3, lo = lane & 7;
    unsigned char* bpb = (unsigned char*)bpw;

    const float* L = logits + ((size_t)h * BATCH + b) * (TT * KK);
    const float4* Lv = (const float4*)L;
    float4* lv = (float4*)llds;
#pragma unroll
    for (int i = 0; i < 8; ++i) lv[tid + 128 * i] = Lv[tid + 128 * i];
    __syncthreads();

    const float* TR = (h == 0) ? trans_t : (h == 1) ? trans_p : trans_m;
    int len = lens[b];
    float trA = TR[lo * 8 + hi];   // even step: kp=lo -> kn=hi
    float trB = TR[hi * 8 + lo];   // odd step:  kp=hi -> kn=lo

    if (wid == 0) {
        // ================= Viterbi wave (bit-exact) =================
        float av = llds[lo];

#define VIT_EVEN(t, LT)                                                        \
    {                                                                          \
        float v0 = av + trA;                                                   \
        float ra = fmaxf(v0, DPPF(v0, 0xB1));                                  \
        float rb = fmaxf(ra, DPPF(ra, 0x4E));                                  \
        float vmax = fmaxf(rb, DPPF(rb, 0x141));                               \
        unsigned long long mk = __ballot(v0 == vmax);                          \
        int vi = __builtin_ctz(((unsigned)(mk >> (lane & 56))) & 0xffu);       \
        if (lo == 0) bpb[(t) * 8 + hi] = (unsigned char)vi;                    \
        av = vmax + (LT);                                                      \
    }
#define VIT_ODD(t, LT)                                                         \
    {                                                                          \
        float v0 = av + trB;                                                   \
        float ra = fmaxf(v0, DPPF(v0, 0x128));                                 \
        float rb = fmaxf(ra, xor16f(ra, lane));                                \
        float vmax = fmaxf(rb, xor32f(rb, lane));                              \
        unsigned long long mk = __ballot(v0 == vmax);                          \
        unsigned long long sel = (mk >> lo) & 0x0101010101010101ULL;           \
        int vi = __builtin_ctzll(sel) >> 3;                                    \
        if (hi == 0) bpb[(t) * 8 + lo] = (unsigned char)vi;                    \
        av = vmax + (LT);                                                      \
    }

        float ltA = llds[8 + hi];
        float ltB = llds[16 + lo];
        for (int t = 1; t <= 509; t += 2) {
            float ltA2 = llds[(t + 2) * 8 + hi];
            int tb = (t + 3 <= 511) ? (t + 3) : 511;
            float ltB2 = llds[tb * 8 + lo];
            VIT_EVEN(t, ltA);
            VIT_ODD(t + 1, ltB);
            ltA = ltA2; ltB = ltB2;
        }
        VIT_EVEN(511, ltA);
#undef VIT_EVEN
#undef VIT_ODD

        float ra = fmaxf(av, DPPF(av, 0x128));
        float rb = fmaxf(ra, xor16f(ra, lane));
        float vmax = fmaxf(rb, xor32f(rb, lane));
        unsigned long long mk = __ballot(av == vmax);
        int last_ = __builtin_ctzll(mk) >> 3;

        asm volatile("" ::: "memory");

        // Phase A: lane l composes bp maps for t in [8l+1, 8l+8]
        int t0 = lane * 8;
        unsigned rw[16];
#pragma unroll
        for (int j = 0; j < 8; ++j) {
            int t = t0 + 1 + j;
            if (t <= 511) { rw[2 * j] = bpw[t * 2]; rw[2 * j + 1] = bpw[t * 2 + 1]; }
            else          { rw[2 * j] = 0x03020100u; rw[2 * j + 1] = 0x07060504u; }
        }
        unsigned sv[8];
#pragma unroll
        for (int i = 0; i < 8; ++i) sv[i] = i;
#pragma unroll
        for (int j = 7; j >= 0; --j) {
            unsigned d0 = rw[2 * j], d1 = rw[2 * j + 1];
#pragma unroll
            for (int i = 0; i < 8; ++i) {
                unsigned s = sv[i];
                unsigned d = (s < 4) ? d0 : d1;
                sv[i] = (d >> (8 * (s & 3))) & 0xffu;
            }
        }
        fmapw[lane][0] = sv[0] | (sv[1] << 8) | (sv[2] << 16) | (sv[3] << 24);
        fmapw[lane][1] = sv[4] | (sv[5] << 8) | (sv[6] << 16) | (sv[7] << 24);
        asm volatile("" ::: "memory");

        if (lane == 0) {
            unsigned cur = (unsigned)last_;
            for (int l = 63; l >= 0; --l) {
                unsigned d = (cur < 4) ? fmapw[l][0] : fmapw[l][1];
                cur = (d >> (8 * (cur & 3))) & 0xffu;
                bnd[l] = (unsigned char)cur;
            }
        }
        asm volatile("" ::: "memory");

        int off = h * 8;
        float* otag = out_tags + b * (3 * TT) + h * TT;
        unsigned curr = (lane == 63) ? (unsigned)last_ : (unsigned)bnd[lane + 1];
#pragma unroll
        for (int j = 7; j >= 0; --j) {
            unsigned d = (curr < 4) ? rw[2 * j] : rw[2 * j + 1];
            curr = (d >> (8 * (curr & 3))) & 0xffu;
            otag[t0 + j] = (float)((int)curr + off);
        }
    } else {
        // ============ CRF wave: multiplicative logsumexp ============
        float EA = __expf(trA);
        float EB = __expf(trB);
        float al0 = llds[lo];
        float c0 = rfl(al0);
        float S = __expf(al0 - c0);
        float Mc = c0;
        float r1 = 0.f, r2 = 0.f, r3 = 0.f;
        const float LN8 = 2.0794415416798357f;

#define LSE_EVEN(t, LT)                                                        \
    {                                                                          \
        float c = rfl(LT) + LN8;                                               \
        float F = __expf((LT) - c);                                            \
        float P = S * EA;                                                      \
        float sa = P + DPPF(P, 0xB1);                                          \
        float sb = sa + DPPF(sa, 0x4E);                                        \
        float ss = sb + DPPF(sb, 0x141);                                       \
        if ((t) < len) { S = ss * F; Mc += c; }                                \
        r1 = r2; r2 = r3; r3 = __logf(rfl(S));                                 \
    }
#define LSE_ODD(t, LT)                                                         \
    {                                                                          \
        float c = rfl(LT) + LN8;                                               \
        float F = __expf((LT) - c);                                            \
        float P = S * EB;                                                      \
        float sa = P + DPPF(P, 0x128);                                         \
        float sb = sa + xor16f(sa, lane);                                      \
        float ss = sb + xor32f(sb, lane);                                      \
        if ((t) < len) { S = ss * F; Mc += c; }                                \
        r1 = r2; r2 = r3; r3 = __logf(rfl(S));                                 \
    }

        float ltA = llds[8 + hi];
        float ltB = llds[16 + lo];
        for (int t = 1; t <= 509; t += 2) {
            if ((t & 3) == 1) {
                float g = r2;
                S *= __expf(-g);
                Mc += g;
            }
            float ltA2 = llds[(t + 2) * 8 + hi];
            int tb = (t + 3 <= 511) ? (t + 3) : 511;
            float ltB2 = llds[tb * 8 + lo];
            LSE_EVEN(t, ltA);
            LSE_ODD(t + 1, ltB);
            ltA = ltA2; ltB = ltB2;
        }
        LSE_EVEN(511, ltA);
#undef LSE_EVEN
#undef LSE_ODD

        float aj = Mc + __logf(S);
        float za = fmaxf(aj, DPPF(aj, 0x128));
        float zb = fmaxf(za, xor16f(za, lane));
        float zmax = fmaxf(zb, xor32f(zb, lane));
        float ze = __expf(aj - zmax);
        float zs = ze + DPPF(ze, 0x128);
        float zs2 = zs + xor16f(zs, lane);
        float zsum = zs2 + xor32f(zs2, lane);
        float logZ = zmax + __logf(zsum);

        const int* lab = labels + b * (3 * TT) + h * TT;
        int off = h * 8;
        float sc = 0.f;
#pragma unroll
        for (int j = 0; j < 8; ++j) {
            int t = lane + 64 * j;
            if (t < len) {
                int tg = lab[t] - off;
                sc += llds[t * 8 + tg];
                if (t >= 1) {
                    int tp = lab[t - 1] - off;
                    sc += TR[tp * 8 + tg];
                }
            }
        }
#pragma unroll
        for (int d = 1; d <= 32; d <<= 1) sc += __shfl_xor(sc, d);

        if (lane == 0) partial[blk] = logZ - sc;
    }
}

// ---------------------------------------------------------------------------
// Kernel 3: deterministic loss reduction (192 partials -> scalar)
// ---------------------------------------------------------------------------
__global__ __launch_bounds__(64) void loss_reduce(
    const float* __restrict__ partial, float* __restrict__ out_loss)
{
    int lane = threadIdx.x;
    float s = partial[lane] + partial[lane + 64] + partial[lane + 128];
#pragma unroll
    for (int d = 1; d <= 32; d <<= 1) s += __shfl_xor(s, d);
    if (lane == 0) *out_loss = s;
}

// ---------------------------------------------------------------------------
extern "C" void kernel_launch(void* const* d_in, const int* in_sizes, int n_in,
                              void* d_out, int out_size, void* d_ws, size_t ws_size,
                              hipStream_t stream) {
    const float* enc    = (const float*)d_in[0];
    const int*   labels = (const int*)d_in[1];
    const int*   lens   = (const int*)d_in[2];
    const float* Wt     = (const float*)d_in[3];
    const float* bt     = (const float*)d_in[4];
    const float* Wp     = (const float*)d_in[5];
    const float* bpv    = (const float*)d_in[6];
    const float* Wm     = (const float*)d_in[7];
    const float* bm     = (const float*)d_in[8];
    const float* tr_t   = (const float*)d_in[9];
    const float* tr_p   = (const float*)d_in[10];
    const float* tr_m   = (const float*)d_in[11];

    float* out = (float*)d_out;
    float* partial = (float*)d_ws;   // 192 floats

    gemm_heads<<<ROWS / 64, 256, 0, stream>>>(enc, Wt, bt, Wp, bpv, Wm, bm, out);
    crf_vit<<<192, 128, 0, stream>>>(out, labels, lens, tr_t, tr_p, tr_m,
                                     out + TAGS_OFF, partial);
    loss_reduce<<<1, 64, 0, stream>>>(partial, out + LOSS_OFF);
}